// Round 9
// baseline (283.347 us; speedup 1.0000x reference)
//
#include <hip/hip_runtime.h>
#include <hip/hip_bf16.h>

// Problem constants (fixed by setup_inputs)
constexpr int B_ = 8;
constexpr int H_ = 120;
constexpr int W_ = 160;
constexpr int N_ = H_ * W_;     // 19200
constexpr int C_ = 96;

constexpr int GX1 = 75;         // pass1 blocks per (s,b)
constexpr int TPB1 = 4;         // tiles of 64 rows per block
constexpr int NT2 = N_ / 64;    // 300

typedef __attribute__((ext_vector_type(8))) short s16x8;
typedef __attribute__((ext_vector_type(4))) short s16x4;
typedef __attribute__((ext_vector_type(4))) float f32x4;

static __device__ inline unsigned short f2bf(float f) {
    unsigned u = __float_as_uint(f);
    return (unsigned short)((u + 0x7FFFu + ((u >> 16) & 1u)) >> 16);
}
static __device__ inline float bf2f(unsigned short h) {
    return __uint_as_float(((unsigned)h) << 16);
}
static __device__ inline void MFMA(f32x4& c, s16x8 a, s16x8 b) {
    c = __builtin_amdgcn_mfma_f32_16x16x32_bf16(a, b, c, 0, 0, 0);
}

// ---------------------------------------------------------------- rope tables (transposed: [48][N])
__global__ void rope_table_kernel(float* __restrict__ csT, float* __restrict__ snT) {
    int idx = blockIdx.x * 256 + threadIdx.x;
    if (idx >= 48 * N_) return;
    int p = idx / N_, n = idx - p * N_;
    int ih = n / W_, iw = n - ih * W_;
    int j = (p < 24) ? p : (p - 24);
    float pos = (p < 24) ? (float)ih : (float)iw;
    float theta = expf(-(float)j * (9.210340371976184f / 24.0f));
    float s, c;
    sincosf(pos * theta, &s, &c);
    csT[idx] = c;
    snT[idx] = s;
}

// ---------------------------------------------------------------- W pre-pack (bf16, fragment order)
__global__ void wpack_kernel(const float* __restrict__ Wqk, const float* __restrict__ Wv,
                             unsigned short* __restrict__ wpack) {
    int i = blockIdx.x * 256 + threadIdx.x;   // fragment index 0..3455
    if (i >= 3456) return;
    int s3 = i / 1152, rem = i - s3 * 1152;
    int cT = rem >> 6, lane = rem & 63;
    int col = cT * 16 + (lane & 15), k0 = s3 * 32 + 8 * (lane >> 4);
    const float* wp = (col < 192) ? (Wqk + col * 96 + k0) : (Wv + (col - 192) * 96 + k0);
    f32x4 wa = *(const f32x4*)wp;
    f32x4 wb = *(const f32x4*)(wp + 4);
    s16x8 wf;
    wf[0] = (short)f2bf(wa[0]); wf[1] = (short)f2bf(wa[1]);
    wf[2] = (short)f2bf(wa[2]); wf[3] = (short)f2bf(wa[3]);
    wf[4] = (short)f2bf(wb[0]); wf[5] = (short)f2bf(wb[1]);
    wf[6] = (short)f2bf(wb[2]); wf[7] = (short)f2bf(wb[3]);
    *(s16x8*)&wpack[i * 8] = wf;
}

// ---------------------------------------------------------------- pass 1 (MFMA, 8 waves, fused shfl-rope)
// wave w: rowg = w>>1 (rows 16*rowg..+16), colg = w&1 (cols colg*144..+144)
__global__ __launch_bounds__(512, 4)
void pass1_kernel(const float* __restrict__ x1, const float* __restrict__ x2,
                  const unsigned short* __restrict__ wpack,
                  const float* __restrict__ bqk, const float* __restrict__ bv,
                  const float* __restrict__ csT, const float* __restrict__ snT,
                  unsigned short* __restrict__ qbuf, unsigned short* __restrict__ vbuf,
                  float* __restrict__ kvpart, float* __restrict__ kmpart)
{
    __shared__ alignas(16) unsigned short Wl[27648];   // 55296 B, frag-order
    __shared__ alignas(16) unsigned short kTl[6144];   // 12288 B, frag-order [96ch][64r], ROPED k
    __shared__ alignas(16) unsigned short vTl[6144];   // 12288 B

    const int tid = threadIdx.x;
    const int l = tid & 63, w = tid >> 6;
    const int rowg = w >> 1, colg = w & 1;
    const int gx = blockIdx.x, b = blockIdx.y, s = blockIdx.z;
    const float* x = s ? x2 : x1;
    const int sb = s * B_ + b;

    // stage W from pre-packed global (coalesced, no conversion)
    for (int i = tid; i < 3456; i += 512)
        *(s16x8*)&Wl[i * 8] = *(const s16x8*)&wpack[i * 8];

    float biasv[9];
#pragma unroll
    for (int j = 0; j < 9; ++j) {
        int col = colg * 144 + j * 16 + (l & 15);
        biasv[j] = (col < 192) ? bqk[col] : bv[col - 192];
    }
    f32x4 kv0 = {}, kv1 = {};
    float kmacc[3] = {};
    __syncthreads();

    for (int t = 0; t < TPB1; ++t) {
        const int n0 = (gx * TPB1 + t) * 64;
        // GEMM: wave computes rows [16*rowg,+16) x cols [144*colg,+144)
        f32x4 acc[9] = {};
        const float* xrow = x + ((size_t)b * N_ + n0 + 16 * rowg + (l & 15)) * 96 + 8 * (l >> 4);
#pragma unroll
        for (int s3 = 0; s3 < 3; ++s3) {
            f32x4 xa = *(const f32x4*)(xrow + s3 * 32);
            f32x4 xb = *(const f32x4*)(xrow + s3 * 32 + 4);
            s16x8 af;
            af[0] = (short)f2bf(xa[0]); af[1] = (short)f2bf(xa[1]);
            af[2] = (short)f2bf(xa[2]); af[3] = (short)f2bf(xa[3]);
            af[4] = (short)f2bf(xb[0]); af[5] = (short)f2bf(xb[1]);
            af[6] = (short)f2bf(xb[2]); af[7] = (short)f2bf(xb[3]);
#pragma unroll
            for (int j = 0; j < 9; ++j) {
                s16x8 bf = *(const s16x8*)&Wl[((s3 * 18 + colg * 9 + j) * 64 + l) * 8];
                MFMA(acc[j], af, bf);
            }
        }
        __syncthreads();   // prev tile's kv-MFMA reads of kTl/vTl complete

        // ---- epilogue
        const int r0 = 16 * rowg + 4 * (l >> 4);
        if (colg == 0) {
            // q: j 0..5 (cols 0..95): elu+1, store pre-rope
            unsigned short* qb = qbuf + ((size_t)sb * N_ + n0) * 96;
#pragma unroll
            for (int j = 0; j < 6; ++j) {
#pragma unroll
                for (int i2 = 0; i2 < 4; ++i2) {
                    float q = acc[j][i2] + biasv[j];
                    q = (q > 0.f) ? q + 1.f : __expf(q);
                    qb[(size_t)(r0 + i2) * 96 + j * 16 + (l & 15)] = f2bf(q);
                }
            }
            // k channels 0..47: j 6..8, chT = j-6, rope pairs p in [0,24)
#pragma unroll
            for (int j = 6; j < 9; ++j) {
                int j3 = j - 6;
                int p = (j3 * 16 + (l & 15)) >> 1;
                f32x4 c4 = *(const f32x4*)(csT + (size_t)p * N_ + n0 + r0);
                f32x4 s4 = *(const f32x4*)(snT + (size_t)p * N_ + n0 + r0);
                float colsum = 0.f;
                s16x4 pk;
#pragma unroll
                for (int i2 = 0; i2 < 4; ++i2) {
                    float k = acc[j][i2] + biasv[j];
                    k = (k > 0.f) ? k + 1.f : __expf(k);
                    colsum += k;
                    float kpart = __shfl_xor(k, 1, 64);
                    float kr = (l & 1) ? fmaf(s4[i2], kpart, c4[i2] * k)
                                       : fmaf(-s4[i2], kpart, c4[i2] * k);
                    pk[i2] = (short)f2bf(kr);
                }
                int chunk = ((r0 >> 5) * 6 + j3) * 64 + ((r0 >> 3) & 3) * 16 + (l & 15);
                *(s16x4*)&kTl[chunk * 8 + (r0 & 7)] = pk;
                colsum += __shfl_xor(colsum, 16, 64);
                colsum += __shfl_xor(colsum, 32, 64);
                kmacc[j3] += colsum;
            }
        } else {
            // k channels 48..95: j 0..2, chT = 3+j, rope pairs p in [24,48)
#pragma unroll
            for (int j = 0; j < 3; ++j) {
                int p = (48 + j * 16 + (l & 15)) >> 1;
                f32x4 c4 = *(const f32x4*)(csT + (size_t)p * N_ + n0 + r0);
                f32x4 s4 = *(const f32x4*)(snT + (size_t)p * N_ + n0 + r0);
                float colsum = 0.f;
                s16x4 pk;
#pragma unroll
                for (int i2 = 0; i2 < 4; ++i2) {
                    float k = acc[j][i2] + biasv[j];
                    k = (k > 0.f) ? k + 1.f : __expf(k);
                    colsum += k;
                    float kpart = __shfl_xor(k, 1, 64);
                    float kr = (l & 1) ? fmaf(s4[i2], kpart, c4[i2] * k)
                                       : fmaf(-s4[i2], kpart, c4[i2] * k);
                    pk[i2] = (short)f2bf(kr);
                }
                int chunk = ((r0 >> 5) * 6 + 3 + j) * 64 + ((r0 >> 3) & 3) * 16 + (l & 15);
                *(s16x4*)&kTl[chunk * 8 + (r0 & 7)] = pk;
                colsum += __shfl_xor(colsum, 16, 64);
                colsum += __shfl_xor(colsum, 32, 64);
                kmacc[j] += colsum;
            }
            // v: j 3..8 (cols 0..95 of v), chT = j-3
            unsigned short* vb = vbuf + ((size_t)sb * N_ + n0) * 96;
#pragma unroll
            for (int j = 3; j < 9; ++j) {
                int j6 = j - 3;
                s16x4 pv;
#pragma unroll
                for (int i2 = 0; i2 < 4; ++i2) {
                    float v = acc[j][i2] + biasv[j];
                    unsigned short hv = f2bf(v);
                    pv[i2] = (short)hv;
                    vb[(size_t)(r0 + i2) * 96 + j6 * 16 + (l & 15)] = hv;
                }
                int chunk = ((r0 >> 5) * 6 + j6) * 64 + ((r0 >> 3) & 3) * 16 + (l & 15);
                *(s16x4*)&vTl[chunk * 8 + (r0 & 7)] = pv;
            }
        }
        __syncthreads();
        // kv += k_roped^T @ v : 12 flat C-tiles; wave w owns f=w (+ f=w+8 for w<4)
        {
            int f = w;
            int h = f >> 2, dT = (f >> 1) & 1, eT = f & 1;
#pragma unroll
            for (int ks = 0; ks < 2; ++ks) {
                s16x8 a = *(const s16x8*)&kTl[(((ks * 6 + (h * 2 + dT)) << 6) + l) * 8];
                s16x8 bb = *(const s16x8*)&vTl[(((ks * 6 + (h * 2 + eT)) << 6) + l) * 8];
                MFMA(kv0, a, bb);
            }
            if (w < 4) {
                f = w + 8;
                h = f >> 2; dT = (f >> 1) & 1; eT = f & 1;
#pragma unroll
                for (int ks = 0; ks < 2; ++ks) {
                    s16x8 a = *(const s16x8*)&kTl[(((ks * 6 + (h * 2 + dT)) << 6) + l) * 8];
                    s16x8 bb = *(const s16x8*)&vTl[(((ks * 6 + (h * 2 + eT)) << 6) + l) * 8];
                    MFMA(kv1, a, bb);
                }
            }
        }
    }
    // write partials
    float* kvp = kvpart + ((size_t)sb * GX1 + gx) * 3072;
    {
        int f = w;
        int h = f >> 2, dT = (f >> 1) & 1, eT = f & 1;
#pragma unroll
        for (int i2 = 0; i2 < 4; ++i2)
            kvp[h * 1024 + (dT * 16 + 4 * (l >> 4) + i2) * 32 + eT * 16 + (l & 15)] = kv0[i2];
        if (w < 4) {
            f = w + 8;
            h = f >> 2; dT = (f >> 1) & 1; eT = f & 1;
#pragma unroll
            for (int i2 = 0; i2 < 4; ++i2)
                kvp[h * 1024 + (dT * 16 + 4 * (l >> 4) + i2) * 32 + eT * 16 + (l & 15)] = kv1[i2];
        }
    }
    if (l < 16) {
        float* kmp = kmpart + ((size_t)((size_t)sb * GX1 + gx) * 8 + w) * 48;
#pragma unroll
        for (int j3 = 0; j3 < 3; ++j3) kmp[j3 * 16 + l] = kmacc[j3];
    }
}

// ---------------------------------------------------------------- reduce (vectorized)
__global__ void reduce_kernel(const float* __restrict__ kvpart, const float* __restrict__ kmpart,
                              float* __restrict__ kvbuf, float* __restrict__ kmbuf)
{
    int idx = blockIdx.x * 256 + threadIdx.x;
    const float invN = 1.0f / (float)N_;
    if (idx < 16 * 768) {                       // kv: f32x4 chunks
        int sb = idx / 768, e4 = idx - sb * 768;
        f32x4 acc = {0.f, 0.f, 0.f, 0.f};
        for (int g = 0; g < GX1; ++g) {
            f32x4 vv = *(const f32x4*)&kvpart[((size_t)sb * GX1 + g) * 3072 + e4 * 4];
            acc[0] += vv[0]; acc[1] += vv[1]; acc[2] += vv[2]; acc[3] += vv[3];
        }
        acc[0] *= invN; acc[1] *= invN; acc[2] *= invN; acc[3] *= invN;
        *(f32x4*)&kvbuf[(size_t)sb * 3072 + e4 * 4] = acc;
    } else if (idx < 16 * 768 + 16 * 96) {
        int j = idx - 16 * 768;
        int sb = j / 96, ch = j - sb * 96;
        int par = ch / 48, c48 = ch - par * 48;   // which wave-parity holds this channel
        float acc = 0.f;
        for (int g = 0; g < GX1; ++g)
#pragma unroll
            for (int rg = 0; rg < 4; ++rg)
                acc += kmpart[((size_t)((size_t)sb * GX1 + g) * 8 + rg * 2 + par) * 48 + c48];
        kmbuf[j] = acc * invN;
    }
}

// ---------------------------------------------------------------- pass 2 (MFMA, aliased LDS)
__global__ __launch_bounds__(256, 5)
void pass2_kernel(const unsigned short* __restrict__ qbuf, const unsigned short* __restrict__ vbuf,
                  const float* __restrict__ kvbuf, const float* __restrict__ kmbuf,
                  const float* __restrict__ csT, const float* __restrict__ snT,
                  const float* __restrict__ lw, const float* __restrict__ lb,
                  float* __restrict__ out)
{
    // aliased region: phase A = qls (13312 B) + kvh (7680 B); phase B = osmT (25344 B)
    __shared__ alignas(16) char pbuf[25344];
    unsigned short* qls = (unsigned short*)pbuf;             // [64][104]
    unsigned short* kvh = (unsigned short*)(pbuf + 13312);   // [h*32+e][40]
    float* osmT = (float*)pbuf;                              // [96][66]
    __shared__ float zsh[192];
    __shared__ float lwL[864], lbL[96], kmL[96];

    const int tid = threadIdx.x, l = tid & 63, w = tid >> 6;
    const int tile = blockIdx.x, b = blockIdx.y, s = blockIdx.z, so = 1 - s;
    const int n0 = tile * 64;
    const int sb = s * B_ + b, sbo = so * B_ + b;

    // stage kv (bf16, transposed to [e][d])
    const float* kvsrc = kvbuf + (size_t)sbo * 3072;
    for (int i = tid; i < 3072; i += 256) {
        float vkv = kvsrc[i];
        int h = i >> 10, d = (i >> 5) & 31, e = i & 31;
        kvh[(h * 32 + e) * 40 + d] = f2bf(vkv);
    }
    for (int i = tid; i < 864; i += 256) lwL[i] = lw[i];
    if (tid < 96) { lbL[tid] = lb[tid]; kmL[tid] = kmbuf[sbo * 96 + tid]; }
    // stage q tile
    const unsigned short* qb = qbuf + ((size_t)sb * N_ + n0) * 96;
    for (int i = tid; i < 768; i += 256) {
        int row = i / 12, seg = i - row * 12;
        *(s16x8*)&qls[row * 104 + seg * 8] = *(const s16x8*)&qb[row * 96 + seg * 8];
    }
    __syncthreads();
    // z from raw q (pre-rope) vs other-stream kmean
    if (tid < 192) {
        int hh = tid >> 6, r = tid & 63;
        float a = 0.f;
        for (int d = 0; d < 32; ++d)
            a += bf2f(qls[r * 104 + hh * 32 + d]) * kmL[hh * 32 + d];
        zsh[hh * 64 + r] = 1.f / (a + 1e-6f);
    }
    __syncthreads();
    // rope q in place
#pragma unroll
    for (int it = 0; it < 12; ++it) {
        int u = it * 256 + tid;
        int r = u & 63, p = u >> 6;
        float c = csT[(size_t)p * N_ + n0 + r];
        float sv = snT[(size_t)p * N_ + n0 + r];
        unsigned int pr = *(unsigned int*)&qls[r * 104 + 2 * p];
        float re = bf2f((unsigned short)(pr & 0xFFFFu));
        float im = bf2f((unsigned short)(pr >> 16));
        unsigned int o0 = f2bf(c * re - sv * im);
        unsigned int o1 = f2bf(sv * re + c * im);
        *(unsigned int*)&qls[r * 104 + 2 * p] = o0 | (o1 << 16);
    }
    __syncthreads();
    // o = rope(q) @ kv  (reads qls,kvh -> regs)
    f32x4 oac[3][2] = {};
#pragma unroll
    for (int h = 0; h < 3; ++h) {
        s16x8 a = *(const s16x8*)&qls[(16 * w + (l & 15)) * 104 + h * 32 + 8 * (l >> 4)];
#pragma unroll
        for (int eT = 0; eT < 2; ++eT) {
            int rowb = (h * 32 + eT * 16 + (l & 15)) * 40 + 8 * (l >> 4);
            MFMA(oac[h][eT], a, *(const s16x8*)&kvh[rowb]);
        }
    }
    __syncthreads();   // all qls/kvh reads done -> safe to overwrite as osmT
#pragma unroll
    for (int h = 0; h < 3; ++h) {
#pragma unroll
        for (int i2 = 0; i2 < 4; ++i2) {
            int row = 16 * w + 4 * (l >> 4) + i2;
            float z = zsh[h * 64 + row];
            osmT[(h * 32 + (l & 15)) * 66 + row] = oac[h][0][i2] * z;
            osmT[(h * 32 + 16 + (l & 15)) * 66 + row] = oac[h][1][i2] * z;
        }
    }
    __syncthreads();
    // LePE conv add: 768 ch-octets (64 r x 12 octets), ch-fast, u16x8 loads
    const unsigned short* vb = vbuf + (size_t)sb * (size_t)N_ * 96;
#pragma unroll
    for (int it = 0; it < 3; ++it) {
        int oct = it * 256 + tid;
        int r = oct / 12, c8 = oct - r * 12;
        int ch0 = c8 * 8;
        int npos = n0 + r, ih = npos / 160, iw = npos - ih * 160;
        float a[8];
#pragma unroll
        for (int e = 0; e < 8; ++e) a[e] = lbL[ch0 + e];
#pragma unroll
        for (int ky = 0; ky < 3; ++ky) {
            int ih2 = ih + ky - 1;
            if ((unsigned)ih2 >= 120u) continue;
#pragma unroll
            for (int kx = 0; kx < 3; ++kx) {
                int iw2 = iw + kx - 1;
                if ((unsigned)iw2 >= 160u) continue;
                s16x8 vv = *(const s16x8*)&vb[((size_t)ih2 * 160 + iw2) * 96 + ch0];
#pragma unroll
                for (int e = 0; e < 8; ++e)
                    a[e] = fmaf(bf2f((unsigned short)vv[e]), lwL[(ch0 + e) * 9 + ky * 3 + kx], a[e]);
            }
        }
#pragma unroll
        for (int e = 0; e < 8; ++e) osmT[(ch0 + e) * 66 + r] += a[e];
    }
    __syncthreads();
    // store transposed: out[sb][ch][n0+r], f32x4 over r
    float* ob = out + (size_t)sb * 96 * N_ + n0;
#pragma unroll
    for (int it = 0; it < 6; ++it) {
        int qq = it * 256 + tid;
        int r4 = (qq & 15) * 4, ch = qq >> 4;
        f32x4 vv;
        vv[0] = osmT[ch * 66 + r4];
        vv[1] = osmT[ch * 66 + r4 + 1];
        vv[2] = osmT[ch * 66 + r4 + 2];
        vv[3] = osmT[ch * 66 + r4 + 3];
        *(f32x4*)&ob[(size_t)ch * N_ + r4] = vv;
    }
}

// ---------------------------------------------------------------- launch
extern "C" void kernel_launch(void* const* d_in, const int* in_sizes, int n_in,
                              void* d_out, int out_size, void* d_ws, size_t ws_size,
                              hipStream_t stream)
{
    const float* x1  = (const float*)d_in[0];
    const float* x2  = (const float*)d_in[1];
    const float* Wqk = (const float*)d_in[2];
    const float* bqk = (const float*)d_in[3];
    const float* Wv  = (const float*)d_in[4];
    const float* bv  = (const float*)d_in[5];
    const float* lw  = (const float*)d_in[6];
    const float* lb  = (const float*)d_in[7];
    float* out = (float*)d_out;

    char* ws = (char*)d_ws;
    size_t off = 0;
    auto alloc = [&](size_t bytes) -> void* {
        void* p = ws + off;
        off = (off + bytes + 255) & ~(size_t)255;
        return p;
    };
    float* csT = (float*)alloc(sizeof(float) * (size_t)N_ * 48);
    float* snT = (float*)alloc(sizeof(float) * (size_t)N_ * 48);
    unsigned short* qbuf = (unsigned short*)alloc(2ull * B_ * N_ * 96 * 2);
    unsigned short* vbuf = (unsigned short*)alloc(2ull * B_ * N_ * 96 * 2);
    float* kvpart = (float*)alloc(16ull * GX1 * 3072 * 4);
    float* kmpart = (float*)alloc(16ull * GX1 * 8 * 48 * 4);
    float* kvbuf  = (float*)alloc(16ull * 3072 * 4);
    float* kmbuf  = (float*)alloc(16ull * 96 * 4);
    unsigned short* wpack = (unsigned short*)alloc(3456ull * 8 * 2);

    hipLaunchKernelGGL(rope_table_kernel, dim3((48 * N_ + 255) / 256), dim3(256), 0, stream, csT, snT);
    hipLaunchKernelGGL(wpack_kernel, dim3(14), dim3(256), 0, stream, Wqk, Wv, wpack);
    hipLaunchKernelGGL(pass1_kernel, dim3(GX1, B_, 2), dim3(512), 0, stream,
                       x1, x2, wpack, bqk, bv, csT, snT, qbuf, vbuf, kvpart, kmpart);
    hipLaunchKernelGGL(reduce_kernel, dim3((16 * 768 + 16 * 96 + 255) / 256), dim3(256), 0, stream,
                       kvpart, kmpart, kvbuf, kmbuf);
    hipLaunchKernelGGL(pass2_kernel, dim3(NT2, B_, 2), dim3(256), 0, stream,
                       qbuf, vbuf, kvbuf, kmbuf, csT, snT, lw, lb, out);
}